// Round 3
// baseline (229.761 us; speedup 1.0000x reference)
//
#include <hip/hip_runtime.h>
#include <hip/hip_bf16.h>

typedef __bf16 bf16x8 __attribute__((ext_vector_type(8)));
typedef float f32x4 __attribute__((ext_vector_type(4)));

__device__ __forceinline__ unsigned short f2bf(float f) {
  unsigned int u = __float_as_uint(f);
  u += 0x7fffu + ((u >> 16) & 1u);
  return (unsigned short)(u >> 16);
}

__device__ __forceinline__ unsigned int pack2(float lo, float hi) {
  __hip_bfloat162 h = __float22bfloat162_rn(float2{lo, hi});
  return *(unsigned int*)&h;
}

__device__ __forceinline__ void load_lds16(const void* g, void* l) {
  __builtin_amdgcn_global_load_lds(
      (const __attribute__((address_space(1))) unsigned int*)g,
      (__attribute__((address_space(3))) unsigned int*)l, 16, 0, 0);
}

// ---------------- elementwise f32 -> bf16 ----------------
__global__ void cvt_x(const float* __restrict__ in, unsigned short* __restrict__ out) {
  size_t i = ((size_t)blockIdx.x * 256 + threadIdx.x) * 4;
  float4 v = *(const float4*)(in + i);
  ushort4 o;
  o.x = f2bf(v.x); o.y = f2bf(v.y); o.z = f2bf(v.z); o.w = f2bf(v.w);
  *(ushort4*)(out + i) = o;
}

// ---------------- transpose f32 [R][C] -> bf16 [C][R] ----------------
__global__ void tr_w(const float* __restrict__ in, unsigned short* __restrict__ out,
                     int ldin, int ldout) {
  __shared__ float tile[32][33];
  const int c0 = blockIdx.x * 32, r0 = blockIdx.y * 32;
  const int tx = threadIdx.x, ty = threadIdx.y;
#pragma unroll
  for (int j = 0; j < 4; ++j)
    tile[ty + j * 8][tx] = in[(size_t)(r0 + ty + j * 8) * ldin + c0 + tx];
  __syncthreads();
#pragma unroll
  for (int j = 0; j < 4; ++j)
    out[(size_t)(c0 + ty + j * 8) * ldout + r0 + tx] = f2bf(tile[tx][ty + j * 8]);
}

// ---------------- V slice of QKV -> VT [b*4+kv][128][2048] ----------------
__global__ void tr_v(const unsigned short* __restrict__ QKV, unsigned short* __restrict__ VT) {
  __shared__ unsigned short tile[32][33];
  const int z = blockIdx.z, b = z >> 2, kvh = z & 3;
  const unsigned short* in = QKV + (size_t)(b * 2048) * 3072 + 2560 + kvh * 128;
  unsigned short* out = VT + (size_t)z * 128 * 2048;
  const int c0 = blockIdx.x * 32, r0 = blockIdx.y * 32;
  const int tx = threadIdx.x, ty = threadIdx.y;
#pragma unroll
  for (int j = 0; j < 4; ++j)
    tile[ty + j * 8][tx] = in[(size_t)(r0 + ty + j * 8) * 3072 + c0 + tx];
  __syncthreads();
#pragma unroll
  for (int j = 0; j < 4; ++j)
    out[(size_t)(c0 + ty + j * 8) * 2048 + r0 + tx] = tile[tx][ty + j * 8];
}

// ---------------- bf16 GEMM: C[M][N] = A[M][K] * B^T[N][K] ----------------
template <int OUTF32>
__global__ void gemm_bt(const unsigned short* __restrict__ A,
                        const unsigned short* __restrict__ B,
                        void* __restrict__ Cv, int M, int N, int K) {
  __shared__ __attribute__((aligned(16))) unsigned short As[128 * 64];
  __shared__ __attribute__((aligned(16))) unsigned short Bs[128 * 64];
  const int tid = threadIdx.x;
  const int lane = tid & 63;
  const int cl = lane & 15, rg = lane >> 4;
  const int wave = tid >> 6;
  const int bm = blockIdx.y, bn = blockIdx.x;
  const int wm = wave >> 1, wn = wave & 1;
  f32x4 acc[4][4] = {};
  const int nk = K >> 6;
  for (int kt = 0; kt < nk; ++kt) {
    const int k0 = kt << 6;
    __syncthreads();
#pragma unroll
    for (int i = 0; i < 8; ++i) {
      const int Ls = (i & 3) * 256 + tid;
      const int r = Ls >> 3, s = Ls & 7;
      const int c = s ^ (r & 7);
      const unsigned short* src;
      unsigned short* dst;
      if (i < 4) {
        src = A + (size_t)(bm * 128 + r) * K + k0 + c * 8;
        dst = As + (((i & 3) * 256 + (tid & 0xC0)) << 3);
      } else {
        src = B + (size_t)(bn * 128 + r) * K + k0 + c * 8;
        dst = Bs + (((i & 3) * 256 + (tid & 0xC0)) << 3);
      }
      load_lds16(src, dst);
    }
    __syncthreads();
#pragma unroll
    for (int ks = 0; ks < 2; ++ks) {
      bf16x8 af[4], bfr[4];
#pragma unroll
      for (int m = 0; m < 4; ++m) {
        const int row = wm * 64 + m * 16 + cl;
        const int p = (ks * 4 + rg) ^ (row & 7);
        af[m] = *(const bf16x8*)(As + row * 64 + p * 8);
      }
#pragma unroll
      for (int n = 0; n < 4; ++n) {
        const int row = wn * 64 + n * 16 + cl;
        const int p = (ks * 4 + rg) ^ (row & 7);
        bfr[n] = *(const bf16x8*)(Bs + row * 64 + p * 8);
      }
#pragma unroll
      for (int m = 0; m < 4; ++m)
#pragma unroll
        for (int n = 0; n < 4; ++n)
          acc[m][n] = __builtin_amdgcn_mfma_f32_16x16x32_bf16(af[m], bfr[n], acc[m][n], 0, 0, 0);
    }
  }
#pragma unroll
  for (int m = 0; m < 4; ++m)
#pragma unroll
    for (int n = 0; n < 4; ++n)
#pragma unroll
      for (int i = 0; i < 4; ++i) {
        const int row = bm * 128 + wm * 64 + m * 16 + rg * 4 + i;
        const int col = bn * 128 + wn * 64 + n * 16 + cl;
        if (OUTF32)
          ((float*)Cv)[(size_t)row * N + col] = acc[m][n][i];
        else
          ((unsigned short*)Cv)[(size_t)row * N + col] = f2bf(acc[m][n][i]);
      }
}

// ---------------- causal GQA flash attention (swapped-operand, reg-P, q=32/wave) ----------------
// Block: 4 waves x 32 q-rows = 128 q. Grid 16 q-tiles, heavy-first (jt = 15 - jp) for LPT balance.
// S^T = mfma(K, Q): col = q = lane&15. Each K/V fragment read feeds both q-subtiles (2x intensity).
__global__ __launch_bounds__(256, 2) void attn(const unsigned short* __restrict__ QKV,
                                               const unsigned short* __restrict__ VT,
                                               unsigned short* __restrict__ O) {
  __shared__ __attribute__((aligned(16))) unsigned short Ks[2][64 * 128];
  __shared__ __attribute__((aligned(16))) unsigned short VTs[2][128 * 64];
  const int T = 2048, LD = 3072, D = 2048;
  const int jt = 15 - blockIdx.x;
  const int h = blockIdx.y, b = blockIdx.z;
  const int kvh = h >> 2;
  const int tid = threadIdx.x, lane = tid & 63, wave = tid >> 6;
  const int cl = lane & 15, rg = lane >> 4;
  const bool abit = (lane & 16) != 0, bbit = (lane & 32) != 0;
  const bool ab = abit != bbit;
  const unsigned short* Kbase = QKV + (size_t)b * T * LD + 2048 + kvh * 128;
  const unsigned short* Vbase = VT + (size_t)(b * 4 + kvh) * 128 * T;

  auto stage = [&](int sb, int k0) {
#pragma unroll
    for (int i = 0; i < 4; ++i) {
      const int Ls = i * 256 + tid;
      const int r = Ls >> 4, s = Ls & 15, c = s ^ (r & 7);
      load_lds16(Kbase + (size_t)(k0 + r) * LD + c * 8,
                 &Ks[sb][(i * 256 + (tid & 0xC0)) * 8]);
    }
#pragma unroll
    for (int i = 0; i < 4; ++i) {
      const int Ls = i * 256 + tid;
      const int r = Ls >> 3, s = Ls & 7, c = s ^ (r & 7);
      load_lds16(Vbase + (size_t)r * T + k0 + c * 8,
                 &VTs[sb][(i * 256 + (tid & 0xC0)) * 8]);
    }
  };

  const float scale = 0.08838834764831845f;  // 1/sqrt(128)
  const int q0 = jt * 128;
  const int nkt = 2 * jt + 2;
  const int qb = q0 + wave * 32;

  bf16x8 qf[2][4];
#pragma unroll
  for (int sub = 0; sub < 2; ++sub) {
    const unsigned short* Qp = QKV + (size_t)(b * T + qb + sub * 16 + cl) * LD + h * 128;
#pragma unroll
    for (int ks = 0; ks < 4; ++ks) qf[sub][ks] = *(const bf16x8*)(Qp + ks * 32 + rg * 8);
  }

  f32x4 o[2][8] = {};
  float mrun[2] = {-1e30f, -1e30f}, lrun[2] = {0.f, 0.f};
  int buf = 0;

  stage(0, 0);
  __syncthreads();

#pragma unroll 1
  for (int kt = 0; kt < nkt; ++kt) {
    if (kt + 1 < nkt) stage(buf ^ 1, (kt + 1) * 64);

    // S^T = K * Q^T : sa[sub][n] rows k = k0+n*16+rg*4+i, col q = cl (per subtile)
    f32x4 sa[2][4] = {};
    __builtin_amdgcn_s_setprio(1);
#pragma unroll
    for (int ks = 0; ks < 4; ++ks) {
#pragma unroll
      for (int n = 0; n < 4; ++n) {
        const int row = n * 16 + cl;
        const int p = (ks * 4 + rg) ^ (row & 7);
        const bf16x8 kf = *(const bf16x8*)(&Ks[buf][row * 128 + p * 8]);
        sa[0][n] = __builtin_amdgcn_mfma_f32_16x16x32_bf16(kf, qf[0][ks], sa[0][n], 0, 0, 0);
        sa[1][n] = __builtin_amdgcn_mfma_f32_16x16x32_bf16(kf, qf[1][ks], sa[1][n], 0, 0, 0);
      }
    }
    __builtin_amdgcn_s_setprio(0);

    const int k0 = kt * 64;
    float p[2][4][4];
    unsigned int F[2][2][4];

#pragma unroll
    for (int sub = 0; sub < 2; ++sub) {
      const int qbs = qb + sub * 16;
      const int qrow = qbs + cl;
      float pmax = -1e30f;
      if (k0 + 63 > qbs) {  // diagonal tile for this subtile
#pragma unroll
        for (int n = 0; n < 4; ++n)
#pragma unroll
          for (int i = 0; i < 4; ++i) {
            const int kg = k0 + n * 16 + rg * 4 + i;
            p[sub][n][i] = (kg > qrow) ? -1e30f : sa[sub][n][i] * scale;
            pmax = fmaxf(pmax, p[sub][n][i]);
          }
      } else {
#pragma unroll
        for (int n = 0; n < 4; ++n)
#pragma unroll
          for (int i = 0; i < 4; ++i) {
            p[sub][n][i] = sa[sub][n][i] * scale;
            pmax = fmaxf(pmax, p[sub][n][i]);
          }
      }
      pmax = fmaxf(pmax, __shfl_xor(pmax, 16));
      pmax = fmaxf(pmax, __shfl_xor(pmax, 32));

      if (!__all(pmax <= mrun[sub] + 8.f)) {  // T13 defer-max
        const float mnew = fmaxf(mrun[sub], pmax);
        const float alpha = __expf(mrun[sub] - mnew);
        mrun[sub] = mnew;
        lrun[sub] *= alpha;
#pragma unroll
        for (int n2 = 0; n2 < 8; ++n2) o[sub][n2] *= alpha;
      }

      float rs = 0.f;
#pragma unroll
      for (int n = 0; n < 4; ++n)
#pragma unroll
        for (int i = 0; i < 4; ++i) {
          p[sub][n][i] = __expf(p[sub][n][i] - mrun[sub]);
          rs += p[sub][n][i];
        }
      rs += __shfl_xor(rs, 16);
      rs += __shfl_xor(rs, 32);
      lrun[sub] += rs;

      // pack P->bf16 pairs and butterfly into PV B-fragment layout
#pragma unroll
      for (int ks2 = 0; ks2 < 2; ++ks2) {
        const unsigned int pk00 = pack2(p[sub][2 * ks2][0], p[sub][2 * ks2][1]);
        const unsigned int pk01 = pack2(p[sub][2 * ks2][2], p[sub][2 * ks2][3]);
        const unsigned int pk10 = pack2(p[sub][2 * ks2 + 1][0], p[sub][2 * ks2 + 1][1]);
        const unsigned int pk11 = pack2(p[sub][2 * ks2 + 1][2], p[sub][2 * ks2 + 1][3]);
        const unsigned int s0 = bbit ? pk00 : pk10;
        const unsigned int s1 = bbit ? pk01 : pk11;
        const unsigned int r0 = (unsigned int)__shfl_xor((int)s0, 32);
        const unsigned int r1 = (unsigned int)__shfl_xor((int)s1, 32);
        const unsigned int gk0 = bbit ? pk10 : pk00;
        const unsigned int gk1 = bbit ? pk11 : pk01;
        const unsigned int t0 = ab ? gk0 : r0;
        const unsigned int t1 = ab ? gk1 : r1;
        const unsigned int u0 = (unsigned int)__shfl_xor((int)t0, 16);
        const unsigned int u1 = (unsigned int)__shfl_xor((int)t1, 16);
        const unsigned int k20 = ab ? r0 : gk0;
        const unsigned int k21 = ab ? r1 : gk1;
        F[sub][ks2][0] = abit ? u0 : k20;
        F[sub][ks2][1] = abit ? u1 : k21;
        F[sub][ks2][2] = abit ? k20 : u0;
        F[sub][ks2][3] = abit ? k21 : u1;
      }
    }

    // O^T += V^T * P : o[sub][n2] rows d = n2*16+rg*4+i, col q = cl; vf shared across subs
    __builtin_amdgcn_s_setprio(1);
#pragma unroll
    for (int ks2 = 0; ks2 < 2; ++ks2) {
      uint4 f0 = make_uint4(F[0][ks2][0], F[0][ks2][1], F[0][ks2][2], F[0][ks2][3]);
      uint4 f1 = make_uint4(F[1][ks2][0], F[1][ks2][1], F[1][ks2][2], F[1][ks2][3]);
      const bf16x8 pf0 = *(const bf16x8*)&f0;
      const bf16x8 pf1 = *(const bf16x8*)&f1;
#pragma unroll
      for (int n2 = 0; n2 < 8; ++n2) {
        const int dr = n2 * 16 + cl;
        const int p2 = (ks2 * 4 + rg) ^ (dr & 7);
        const bf16x8 vf = *(const bf16x8*)(&VTs[buf][dr * 64 + p2 * 8]);
        o[0][n2] = __builtin_amdgcn_mfma_f32_16x16x32_bf16(vf, pf0, o[0][n2], 0, 0, 0);
        o[1][n2] = __builtin_amdgcn_mfma_f32_16x16x32_bf16(vf, pf1, o[1][n2], 0, 0, 0);
      }
    }
    __builtin_amdgcn_s_setprio(0);

    __syncthreads();
    buf ^= 1;
  }

#pragma unroll
  for (int sub = 0; sub < 2; ++sub) {
    const int qrow = qb + sub * 16 + cl;
    const float rl = __builtin_amdgcn_rcpf(lrun[sub]);
#pragma unroll
    for (int n2 = 0; n2 < 8; ++n2) {
      ushort4 ov;
      ov.x = f2bf(o[sub][n2][0] * rl);
      ov.y = f2bf(o[sub][n2][1] * rl);
      ov.z = f2bf(o[sub][n2][2] * rl);
      ov.w = f2bf(o[sub][n2][3] * rl);
      *(ushort4*)(O + (size_t)(b * T + qrow) * D + h * 128 + n2 * 16 + rg * 4) = ov;
    }
  }
}

extern "C" void kernel_launch(void* const* d_in, const int* in_sizes, int n_in,
                              void* d_out, int out_size, void* d_ws, size_t ws_size,
                              hipStream_t stream) {
  const float* x = (const float*)d_in[0];
  const float* Wq = (const float*)d_in[1];
  const float* Wk = (const float*)d_in[2];
  const float* Wv = (const float*)d_in[3];
  const float* Wo = (const float*)d_in[4];
  float* out = (float*)d_out;

  char* ws = (char*)d_ws;
  unsigned short* xb    = (unsigned short*)(ws);                 // x bf16, later attn O
  unsigned short* WqkvT = (unsigned short*)(ws + 16777216);      // [3072][2048]
  unsigned short* WoT   = (unsigned short*)(ws + 29360128);      // [2048][2048]
  unsigned short* QKV   = (unsigned short*)(ws + 37748736);      // [4096][3072]
  unsigned short* VTb   = (unsigned short*)(ws + 62914560);      // [8][128][2048]

  cvt_x<<<dim3(8192), dim3(256), 0, stream>>>(x, xb);
  tr_w<<<dim3(64, 64), dim3(32, 8), 0, stream>>>(Wq, WqkvT, 2048, 2048);
  tr_w<<<dim3(16, 64), dim3(32, 8), 0, stream>>>(Wk, WqkvT + (size_t)2048 * 2048, 512, 2048);
  tr_w<<<dim3(16, 64), dim3(32, 8), 0, stream>>>(Wv, WqkvT + (size_t)2560 * 2048, 512, 2048);
  tr_w<<<dim3(64, 64), dim3(32, 8), 0, stream>>>(Wo, WoT, 2048, 2048);

  gemm_bt<0><<<dim3(24, 32), dim3(256), 0, stream>>>(xb, WqkvT, QKV, 4096, 3072, 2048);
  tr_v<<<dim3(4, 64, 8), dim3(32, 8), 0, stream>>>(QKV, VTb);
  attn<<<dim3(16, 16, 2), dim3(256), 0, stream>>>(QKV, VTb, xb);
  gemm_bt<1><<<dim3(16, 32), dim3(256), 0, stream>>>(xb, WoT, out, 4096, 2048, 2048);
}

// Round 4
// 223.314 us; speedup vs baseline: 1.0289x; 1.0289x over previous
//
#include <hip/hip_runtime.h>
#include <hip/hip_bf16.h>

typedef __bf16 bf16x8 __attribute__((ext_vector_type(8)));
typedef float f32x4 __attribute__((ext_vector_type(4)));

__device__ __forceinline__ unsigned short f2bf(float f) {
  unsigned int u = __float_as_uint(f);
  u += 0x7fffu + ((u >> 16) & 1u);
  return (unsigned short)(u >> 16);
}

__device__ __forceinline__ unsigned int pack2(float lo, float hi) {
  __hip_bfloat162 h = __float22bfloat162_rn(float2{lo, hi});
  return *(unsigned int*)&h;
}

__device__ __forceinline__ void load_lds16(const void* g, void* l) {
  __builtin_amdgcn_global_load_lds(
      (const __attribute__((address_space(1))) unsigned int*)g,
      (__attribute__((address_space(3))) unsigned int*)l, 16, 0, 0);
}

// ---------------- elementwise f32 -> bf16 ----------------
__global__ void cvt_x(const float* __restrict__ in, unsigned short* __restrict__ out) {
  size_t i = ((size_t)blockIdx.x * 256 + threadIdx.x) * 4;
  float4 v = *(const float4*)(in + i);
  ushort4 o;
  o.x = f2bf(v.x); o.y = f2bf(v.y); o.z = f2bf(v.z); o.w = f2bf(v.w);
  *(ushort4*)(out + i) = o;
}

// ---------------- transpose f32 [R][C] -> bf16 [C][R] ----------------
__global__ void tr_w(const float* __restrict__ in, unsigned short* __restrict__ out,
                     int ldin, int ldout) {
  __shared__ float tile[32][33];
  const int c0 = blockIdx.x * 32, r0 = blockIdx.y * 32;
  const int tx = threadIdx.x, ty = threadIdx.y;
#pragma unroll
  for (int j = 0; j < 4; ++j)
    tile[ty + j * 8][tx] = in[(size_t)(r0 + ty + j * 8) * ldin + c0 + tx];
  __syncthreads();
#pragma unroll
  for (int j = 0; j < 4; ++j)
    out[(size_t)(c0 + ty + j * 8) * ldout + r0 + tx] = f2bf(tile[tx][ty + j * 8]);
}

// ---------------- V slice of QKV -> VT [b*4+kv][128][2048] ----------------
__global__ void tr_v(const unsigned short* __restrict__ QKV, unsigned short* __restrict__ VT) {
  __shared__ unsigned short tile[32][33];
  const int z = blockIdx.z, b = z >> 2, kvh = z & 3;
  const unsigned short* in = QKV + (size_t)(b * 2048) * 3072 + 2560 + kvh * 128;
  unsigned short* out = VT + (size_t)z * 128 * 2048;
  const int c0 = blockIdx.x * 32, r0 = blockIdx.y * 32;
  const int tx = threadIdx.x, ty = threadIdx.y;
#pragma unroll
  for (int j = 0; j < 4; ++j)
    tile[ty + j * 8][tx] = in[(size_t)(r0 + ty + j * 8) * 3072 + c0 + tx];
  __syncthreads();
#pragma unroll
  for (int j = 0; j < 4; ++j)
    out[(size_t)(c0 + ty + j * 8) * 2048 + r0 + tx] = tile[tx][ty + j * 8];
}

// ---------------- bf16 GEMM: C[M][N] = A[M][K] * B^T[N][K] ----------------
template <int OUTF32>
__global__ void gemm_bt(const unsigned short* __restrict__ A,
                        const unsigned short* __restrict__ B,
                        void* __restrict__ Cv, int M, int N, int K) {
  __shared__ __attribute__((aligned(16))) unsigned short As[128 * 64];
  __shared__ __attribute__((aligned(16))) unsigned short Bs[128 * 64];
  const int tid = threadIdx.x;
  const int lane = tid & 63;
  const int cl = lane & 15, rg = lane >> 4;
  const int wave = tid >> 6;
  const int bm = blockIdx.y, bn = blockIdx.x;
  const int wm = wave >> 1, wn = wave & 1;
  f32x4 acc[4][4] = {};
  const int nk = K >> 6;
  for (int kt = 0; kt < nk; ++kt) {
    const int k0 = kt << 6;
    __syncthreads();
#pragma unroll
    for (int i = 0; i < 8; ++i) {
      const int Ls = (i & 3) * 256 + tid;
      const int r = Ls >> 3, s = Ls & 7;
      const int c = s ^ (r & 7);
      const unsigned short* src;
      unsigned short* dst;
      if (i < 4) {
        src = A + (size_t)(bm * 128 + r) * K + k0 + c * 8;
        dst = As + (((i & 3) * 256 + (tid & 0xC0)) << 3);
      } else {
        src = B + (size_t)(bn * 128 + r) * K + k0 + c * 8;
        dst = Bs + (((i & 3) * 256 + (tid & 0xC0)) << 3);
      }
      load_lds16(src, dst);
    }
    __syncthreads();
#pragma unroll
    for (int ks = 0; ks < 2; ++ks) {
      bf16x8 af[4], bfr[4];
#pragma unroll
      for (int m = 0; m < 4; ++m) {
        const int row = wm * 64 + m * 16 + cl;
        const int p = (ks * 4 + rg) ^ (row & 7);
        af[m] = *(const bf16x8*)(As + row * 64 + p * 8);
      }
#pragma unroll
      for (int n = 0; n < 4; ++n) {
        const int row = wn * 64 + n * 16 + cl;
        const int p = (ks * 4 + rg) ^ (row & 7);
        bfr[n] = *(const bf16x8*)(Bs + row * 64 + p * 8);
      }
#pragma unroll
      for (int m = 0; m < 4; ++m)
#pragma unroll
        for (int n = 0; n < 4; ++n)
          acc[m][n] = __builtin_amdgcn_mfma_f32_16x16x32_bf16(af[m], bfr[n], acc[m][n], 0, 0, 0);
    }
  }
#pragma unroll
  for (int m = 0; m < 4; ++m)
#pragma unroll
    for (int n = 0; n < 4; ++n)
#pragma unroll
      for (int i = 0; i < 4; ++i) {
        const int row = bm * 128 + wm * 64 + m * 16 + rg * 4 + i;
        const int col = bn * 128 + wn * 64 + n * 16 + cl;
        if (OUTF32)
          ((float*)Cv)[(size_t)row * N + col] = acc[m][n][i];
        else
          ((unsigned short*)Cv)[(size_t)row * N + col] = f2bf(acc[m][n][i]);
      }
}

// ---------------- causal GQA flash attention (swapped-operand, reg-P, q=32/wave, paired) ----------------
// Block: 4 waves x 32 q-rows = 128-row q-tile. Each block does tiles (15-jp, jp): 34 k-iters, uniform.
// S^T = mfma(K, Q): col = q = lane&15. Each K/V fragment read feeds both q-subtiles (2x intensity).
__global__ __launch_bounds__(256, 2) void attn(const unsigned short* __restrict__ QKV,
                                               const unsigned short* __restrict__ VT,
                                               unsigned short* __restrict__ O) {
  __shared__ __attribute__((aligned(16))) unsigned short Ks[2][64 * 128];
  __shared__ __attribute__((aligned(16))) unsigned short VTs[2][128 * 64];
  const int T = 2048, LD = 3072, D = 2048;
  const int jp = blockIdx.x;
  const int h = blockIdx.y, b = blockIdx.z;
  const int kvh = h >> 2;
  const int tid = threadIdx.x, lane = tid & 63, wave = tid >> 6;
  const int cl = lane & 15, rg = lane >> 4;
  const bool abit = (lane & 16) != 0, bbit = (lane & 32) != 0;
  const bool ab = abit != bbit;
  const unsigned short* Kbase = QKV + (size_t)b * T * LD + 2048 + kvh * 128;
  const unsigned short* Vbase = VT + (size_t)(b * 4 + kvh) * 128 * T;

  auto stage = [&](int sb, int k0) {
#pragma unroll
    for (int i = 0; i < 4; ++i) {
      const int Ls = i * 256 + tid;
      const int r = Ls >> 4, s = Ls & 15, c = s ^ (r & 7);
      load_lds16(Kbase + (size_t)(k0 + r) * LD + c * 8,
                 &Ks[sb][(i * 256 + (tid & 0xC0)) * 8]);
    }
#pragma unroll
    for (int i = 0; i < 4; ++i) {
      const int Ls = i * 256 + tid;
      const int r = Ls >> 3, s = Ls & 7, c = s ^ (r & 7);
      load_lds16(Vbase + (size_t)r * T + k0 + c * 8,
                 &VTs[sb][(i * 256 + (tid & 0xC0)) * 8]);
    }
  };

  const float scale = 0.08838834764831845f;  // 1/sqrt(128)

#pragma unroll 1
  for (int pass = 0; pass < 2; ++pass) {
    const int jt = pass ? jp : (15 - jp);
    const int q0 = jt * 128;
    const int nkt = 2 * jt + 2;
    const int qb = q0 + wave * 32;

    bf16x8 qf[2][4];
#pragma unroll
    for (int sub = 0; sub < 2; ++sub) {
      const unsigned short* Qp = QKV + (size_t)(b * T + qb + sub * 16 + cl) * LD + h * 128;
#pragma unroll
      for (int ks = 0; ks < 4; ++ks) qf[sub][ks] = *(const bf16x8*)(Qp + ks * 32 + rg * 8);
    }

    f32x4 o[2][8] = {};
    float mrun[2] = {-1e30f, -1e30f}, lrun[2] = {0.f, 0.f};
    int buf = 0;

    stage(0, 0);
    __syncthreads();

#pragma unroll 1
    for (int kt = 0; kt < nkt; ++kt) {
      if (kt + 1 < nkt) stage(buf ^ 1, (kt + 1) * 64);

      // S^T = K * Q^T : sa[sub][n] rows k = k0+n*16+rg*4+i, col q = cl (per subtile)
      f32x4 sa[2][4] = {};
      __builtin_amdgcn_s_setprio(1);
#pragma unroll
      for (int ks = 0; ks < 4; ++ks) {
#pragma unroll
        for (int n = 0; n < 4; ++n) {
          const int row = n * 16 + cl;
          const int p = (ks * 4 + rg) ^ (row & 7);
          const bf16x8 kf = *(const bf16x8*)(&Ks[buf][row * 128 + p * 8]);
          sa[0][n] = __builtin_amdgcn_mfma_f32_16x16x32_bf16(kf, qf[0][ks], sa[0][n], 0, 0, 0);
          sa[1][n] = __builtin_amdgcn_mfma_f32_16x16x32_bf16(kf, qf[1][ks], sa[1][n], 0, 0, 0);
        }
      }
      __builtin_amdgcn_s_setprio(0);

      const int k0 = kt * 64;
      float p[2][4][4];
      unsigned int F[2][2][4];

#pragma unroll
      for (int sub = 0; sub < 2; ++sub) {
        const int qbs = qb + sub * 16;
        const int qrow = qbs + cl;
        float pmax = -1e30f;
        if (k0 + 63 > qbs) {  // diagonal tile for this subtile
#pragma unroll
          for (int n = 0; n < 4; ++n)
#pragma unroll
            for (int i = 0; i < 4; ++i) {
              const int kg = k0 + n * 16 + rg * 4 + i;
              p[sub][n][i] = (kg > qrow) ? -1e30f : sa[sub][n][i] * scale;
              pmax = fmaxf(pmax, p[sub][n][i]);
            }
        } else {
#pragma unroll
          for (int n = 0; n < 4; ++n)
#pragma unroll
            for (int i = 0; i < 4; ++i) {
              p[sub][n][i] = sa[sub][n][i] * scale;
              pmax = fmaxf(pmax, p[sub][n][i]);
            }
        }
        pmax = fmaxf(pmax, __shfl_xor(pmax, 16));
        pmax = fmaxf(pmax, __shfl_xor(pmax, 32));

        if (!__all(pmax <= mrun[sub] + 8.f)) {  // T13 defer-max
          const float mnew = fmaxf(mrun[sub], pmax);
          const float alpha = __expf(mrun[sub] - mnew);
          mrun[sub] = mnew;
          lrun[sub] *= alpha;
#pragma unroll
          for (int n2 = 0; n2 < 8; ++n2) o[sub][n2] *= alpha;
        }

        float rs = 0.f;
#pragma unroll
        for (int n = 0; n < 4; ++n)
#pragma unroll
          for (int i = 0; i < 4; ++i) {
            p[sub][n][i] = __expf(p[sub][n][i] - mrun[sub]);
            rs += p[sub][n][i];
          }
        rs += __shfl_xor(rs, 16);
        rs += __shfl_xor(rs, 32);
        lrun[sub] += rs;

        // pack P->bf16 pairs and butterfly into PV B-fragment layout
#pragma unroll
        for (int ks2 = 0; ks2 < 2; ++ks2) {
          const unsigned int pk00 = pack2(p[sub][2 * ks2][0], p[sub][2 * ks2][1]);
          const unsigned int pk01 = pack2(p[sub][2 * ks2][2], p[sub][2 * ks2][3]);
          const unsigned int pk10 = pack2(p[sub][2 * ks2 + 1][0], p[sub][2 * ks2 + 1][1]);
          const unsigned int pk11 = pack2(p[sub][2 * ks2 + 1][2], p[sub][2 * ks2 + 1][3]);
          const unsigned int s0 = bbit ? pk00 : pk10;
          const unsigned int s1 = bbit ? pk01 : pk11;
          const unsigned int r0 = (unsigned int)__shfl_xor((int)s0, 32);
          const unsigned int r1 = (unsigned int)__shfl_xor((int)s1, 32);
          const unsigned int gk0 = bbit ? pk10 : pk00;
          const unsigned int gk1 = bbit ? pk11 : pk01;
          const unsigned int t0 = ab ? gk0 : r0;
          const unsigned int t1 = ab ? gk1 : r1;
          const unsigned int u0 = (unsigned int)__shfl_xor((int)t0, 16);
          const unsigned int u1 = (unsigned int)__shfl_xor((int)t1, 16);
          const unsigned int k20 = ab ? r0 : gk0;
          const unsigned int k21 = ab ? r1 : gk1;
          F[sub][ks2][0] = abit ? u0 : k20;
          F[sub][ks2][1] = abit ? u1 : k21;
          F[sub][ks2][2] = abit ? k20 : u0;
          F[sub][ks2][3] = abit ? k21 : u1;
        }
      }

      // O^T += V^T * P : o[sub][n2] rows d = n2*16+rg*4+i, col q = cl; vf shared across subs
      __builtin_amdgcn_s_setprio(1);
#pragma unroll
      for (int ks2 = 0; ks2 < 2; ++ks2) {
        uint4 f0 = make_uint4(F[0][ks2][0], F[0][ks2][1], F[0][ks2][2], F[0][ks2][3]);
        uint4 f1 = make_uint4(F[1][ks2][0], F[1][ks2][1], F[1][ks2][2], F[1][ks2][3]);
        const bf16x8 pf0 = *(const bf16x8*)&f0;
        const bf16x8 pf1 = *(const bf16x8*)&f1;
#pragma unroll
        for (int n2 = 0; n2 < 8; ++n2) {
          const int dr = n2 * 16 + cl;
          const int p2 = (ks2 * 4 + rg) ^ (dr & 7);
          const bf16x8 vf = *(const bf16x8*)(&VTs[buf][dr * 64 + p2 * 8]);
          o[0][n2] = __builtin_amdgcn_mfma_f32_16x16x32_bf16(vf, pf0, o[0][n2], 0, 0, 0);
          o[1][n2] = __builtin_amdgcn_mfma_f32_16x16x32_bf16(vf, pf1, o[1][n2], 0, 0, 0);
        }
      }
      __builtin_amdgcn_s_setprio(0);

      __syncthreads();
      buf ^= 1;
    }

#pragma unroll
    for (int sub = 0; sub < 2; ++sub) {
      const int qrow = qb + sub * 16 + cl;
      const float rl = __builtin_amdgcn_rcpf(lrun[sub]);
#pragma unroll
      for (int n2 = 0; n2 < 8; ++n2) {
        ushort4 ov;
        ov.x = f2bf(o[sub][n2][0] * rl);
        ov.y = f2bf(o[sub][n2][1] * rl);
        ov.z = f2bf(o[sub][n2][2] * rl);
        ov.w = f2bf(o[sub][n2][3] * rl);
        *(ushort4*)(O + (size_t)(b * T + qrow) * D + h * 128 + n2 * 16 + rg * 4) = ov;
      }
    }
  }
}

extern "C" void kernel_launch(void* const* d_in, const int* in_sizes, int n_in,
                              void* d_out, int out_size, void* d_ws, size_t ws_size,
                              hipStream_t stream) {
  const float* x = (const float*)d_in[0];
  const float* Wq = (const float*)d_in[1];
  const float* Wk = (const float*)d_in[2];
  const float* Wv = (const float*)d_in[3];
  const float* Wo = (const float*)d_in[4];
  float* out = (float*)d_out;

  char* ws = (char*)d_ws;
  unsigned short* xb    = (unsigned short*)(ws);                 // x bf16, later attn O
  unsigned short* WqkvT = (unsigned short*)(ws + 16777216);      // [3072][2048]
  unsigned short* WoT   = (unsigned short*)(ws + 29360128);      // [2048][2048]
  unsigned short* QKV   = (unsigned short*)(ws + 37748736);      // [4096][3072]
  unsigned short* VTb   = (unsigned short*)(ws + 62914560);      // [8][128][2048]

  cvt_x<<<dim3(8192), dim3(256), 0, stream>>>(x, xb);
  tr_w<<<dim3(64, 64), dim3(32, 8), 0, stream>>>(Wq, WqkvT, 2048, 2048);
  tr_w<<<dim3(16, 64), dim3(32, 8), 0, stream>>>(Wk, WqkvT + (size_t)2048 * 2048, 512, 2048);
  tr_w<<<dim3(16, 64), dim3(32, 8), 0, stream>>>(Wv, WqkvT + (size_t)2560 * 2048, 512, 2048);
  tr_w<<<dim3(64, 64), dim3(32, 8), 0, stream>>>(Wo, WoT, 2048, 2048);

  gemm_bt<0><<<dim3(24, 32), dim3(256), 0, stream>>>(xb, WqkvT, QKV, 4096, 3072, 2048);
  tr_v<<<dim3(4, 64, 8), dim3(32, 8), 0, stream>>>(QKV, VTb);
  attn<<<dim3(8, 16, 2), dim3(256), 0, stream>>>(QKV, VTb, xb);
  gemm_bt<1><<<dim3(16, 32), dim3(256), 0, stream>>>(xb, WoT, out, 4096, 2048, 2048);
}

// Round 5
// 197.872 us; speedup vs baseline: 1.1612x; 1.1286x over previous
//
#include <hip/hip_runtime.h>
#include <hip/hip_bf16.h>

typedef __bf16 bf16x8 __attribute__((ext_vector_type(8)));
typedef float f32x4 __attribute__((ext_vector_type(4)));

__device__ __forceinline__ unsigned short f2bf(float f) {
  unsigned int u = __float_as_uint(f);
  u += 0x7fffu + ((u >> 16) & 1u);
  return (unsigned short)(u >> 16);
}

__device__ __forceinline__ unsigned int pack2(float lo, float hi) {
  __hip_bfloat162 h = __float22bfloat162_rn(float2{lo, hi});
  return *(unsigned int*)&h;
}

__device__ __forceinline__ void load_lds16(const void* g, void* l) {
  __builtin_amdgcn_global_load_lds(
      (const __attribute__((address_space(1))) unsigned int*)g,
      (__attribute__((address_space(3))) unsigned int*)l, 16, 0, 0);
}

// ---------------- elementwise f32 -> bf16 ----------------
__global__ void cvt_x(const float* __restrict__ in, unsigned short* __restrict__ out) {
  size_t i = ((size_t)blockIdx.x * 256 + threadIdx.x) * 4;
  float4 v = *(const float4*)(in + i);
  ushort4 o;
  o.x = f2bf(v.x); o.y = f2bf(v.y); o.z = f2bf(v.z); o.w = f2bf(v.w);
  *(ushort4*)(out + i) = o;
}

// ---------------- transpose f32 [R][C] -> bf16 [C][R] ----------------
__global__ void tr_w(const float* __restrict__ in, unsigned short* __restrict__ out,
                     int ldin, int ldout) {
  __shared__ float tile[32][33];
  const int c0 = blockIdx.x * 32, r0 = blockIdx.y * 32;
  const int tx = threadIdx.x, ty = threadIdx.y;
#pragma unroll
  for (int j = 0; j < 4; ++j)
    tile[ty + j * 8][tx] = in[(size_t)(r0 + ty + j * 8) * ldin + c0 + tx];
  __syncthreads();
#pragma unroll
  for (int j = 0; j < 4; ++j)
    out[(size_t)(c0 + ty + j * 8) * ldout + r0 + tx] = f2bf(tile[tx][ty + j * 8]);
}

// ---------------- V slice of QKV -> VT [b*4+kv][128][2048] ----------------
__global__ void tr_v(const unsigned short* __restrict__ QKV, unsigned short* __restrict__ VT) {
  __shared__ unsigned short tile[32][33];
  const int z = blockIdx.z, b = z >> 2, kvh = z & 3;
  const unsigned short* in = QKV + (size_t)(b * 2048) * 3072 + 2560 + kvh * 128;
  unsigned short* out = VT + (size_t)z * 128 * 2048;
  const int c0 = blockIdx.x * 32, r0 = blockIdx.y * 32;
  const int tx = threadIdx.x, ty = threadIdx.y;
#pragma unroll
  for (int j = 0; j < 4; ++j)
    tile[ty + j * 8][tx] = in[(size_t)(r0 + ty + j * 8) * 3072 + c0 + tx];
  __syncthreads();
#pragma unroll
  for (int j = 0; j < 4; ++j)
    out[(size_t)(c0 + ty + j * 8) * 2048 + r0 + tx] = tile[tx][ty + j * 8];
}

// ---------------- bf16 GEMM 128^2 (kept for Wo): C[M][N] = A[M][K] * B^T[N][K] ----------------
template <int OUTF32>
__global__ void gemm_bt(const unsigned short* __restrict__ A,
                        const unsigned short* __restrict__ B,
                        void* __restrict__ Cv, int M, int N, int K) {
  __shared__ __attribute__((aligned(16))) unsigned short As[128 * 64];
  __shared__ __attribute__((aligned(16))) unsigned short Bs[128 * 64];
  const int tid = threadIdx.x;
  const int lane = tid & 63;
  const int cl = lane & 15, rg = lane >> 4;
  const int wave = tid >> 6;
  const int bm = blockIdx.y, bn = blockIdx.x;
  const int wm = wave >> 1, wn = wave & 1;
  f32x4 acc[4][4] = {};
  const int nk = K >> 6;
  for (int kt = 0; kt < nk; ++kt) {
    const int k0 = kt << 6;
    __syncthreads();
#pragma unroll
    for (int i = 0; i < 8; ++i) {
      const int Ls = (i & 3) * 256 + tid;
      const int r = Ls >> 3, s = Ls & 7;
      const int c = s ^ (r & 7);
      const unsigned short* src;
      unsigned short* dst;
      if (i < 4) {
        src = A + (size_t)(bm * 128 + r) * K + k0 + c * 8;
        dst = As + (((i & 3) * 256 + (tid & 0xC0)) << 3);
      } else {
        src = B + (size_t)(bn * 128 + r) * K + k0 + c * 8;
        dst = Bs + (((i & 3) * 256 + (tid & 0xC0)) << 3);
      }
      load_lds16(src, dst);
    }
    __syncthreads();
#pragma unroll
    for (int ks = 0; ks < 2; ++ks) {
      bf16x8 af[4], bfr[4];
#pragma unroll
      for (int m = 0; m < 4; ++m) {
        const int row = wm * 64 + m * 16 + cl;
        const int p = (ks * 4 + rg) ^ (row & 7);
        af[m] = *(const bf16x8*)(As + row * 64 + p * 8);
      }
#pragma unroll
      for (int n = 0; n < 4; ++n) {
        const int row = wn * 64 + n * 16 + cl;
        const int p = (ks * 4 + rg) ^ (row & 7);
        bfr[n] = *(const bf16x8*)(Bs + row * 64 + p * 8);
      }
#pragma unroll
      for (int m = 0; m < 4; ++m)
#pragma unroll
        for (int n = 0; n < 4; ++n)
          acc[m][n] = __builtin_amdgcn_mfma_f32_16x16x32_bf16(af[m], bfr[n], acc[m][n], 0, 0, 0);
    }
  }
#pragma unroll
  for (int m = 0; m < 4; ++m)
#pragma unroll
    for (int n = 0; n < 4; ++n)
#pragma unroll
      for (int i = 0; i < 4; ++i) {
        const int row = bm * 128 + wm * 64 + m * 16 + rg * 4 + i;
        const int col = bn * 128 + wn * 64 + n * 16 + cl;
        if (OUTF32)
          ((float*)Cv)[(size_t)row * N + col] = acc[m][n][i];
        else
          ((unsigned short*)Cv)[(size_t)row * N + col] = f2bf(acc[m][n][i]);
      }
}

// ---------------- bf16 GEMM 256^2 8-phase (T2+T3+T4+T5): C = A[M][K] * B^T[N][K] ----------------
// 512 threads = 8 waves (2M x 4N). BK=64 as two K-halves of 32. LDS ring: per operand
// 2 buffers x 2 k-halves of [256 rows][32 k] (16 KiB each) = 128 KiB total.
// Chunk permutation L = r*4 + (c ^ ((r>>1)&3)) applied to BOTH the pre-swizzled global
// source (global_load_lds writes linearly) and the ds_read address -> conflict-free reads.
// Counted vmcnt(4) at ends of phases 1 and 3 only (never 0 mid-loop).
template <int OUTF32>
__global__ __launch_bounds__(512, 2) void gemm256(const unsigned short* __restrict__ A,
                                                  const unsigned short* __restrict__ B,
                                                  void* __restrict__ Cv, int M, int N, int K) {
  __shared__ __attribute__((aligned(16))) unsigned short lds[2][2][2][256 * 32];
  const int tid = threadIdx.x;
  const int lane = tid & 63;
  const int cl = lane & 15, rg = lane >> 4;
  const int wave = tid >> 6;
  const int wm = wave >> 2, wn = wave & 3;
  const int bm = blockIdx.y, bn = blockIdx.x;
  const int NK = K >> 6;
  const int rowA = bm * 256, rowB = bn * 256;

  f32x4 acc[8][4] = {};

  // stage one half-slot: 2 x global_load_lds per thread (chunks L = tid, tid+512)
  auto stage_half = [&](int buf, int op, int h, const unsigned short* Mat, int rb, int kt) {
#pragma unroll
    for (int i = 0; i < 2; ++i) {
      const int L = i * 512 + tid;
      const int r = L >> 2;
      const int c = (L & 3) ^ ((r >> 1) & 3);
      const unsigned short* src = Mat + (size_t)(rb + r) * K + kt * 64 + h * 32 + c * 8;
      load_lds16(src, (void*)(&lds[buf][op][h][0] + (size_t)(i * 512 + (tid & ~63)) * 8));
    }
  };

  // prologue: stage tile 0, order A0,B0,A1,B1; wait first two halves
  stage_half(0, 0, 0, A, rowA, 0);
  stage_half(0, 1, 0, B, rowB, 0);
  stage_half(0, 0, 1, A, rowA, 0);
  stage_half(0, 1, 1, B, rowB, 0);
  asm volatile("s_waitcnt vmcnt(4)" ::: "memory");
  __builtin_amdgcn_s_barrier();

  int buf = 0;
#pragma unroll 1
  for (int kt = 0; kt < NK; ++kt) {
    const bool nl = (kt + 1 < NK);
    bf16x8 af[4], bfr[4];

    // ---- phase 0: kk=0, mh=0 : read 4 A-frags + 4 B-frags, stage A-h0(kt+1) ----
#pragma unroll
    for (int f = 0; f < 4; ++f) {
      const int r = 128 * wm + 16 * f + cl;
      af[f] = *(const bf16x8*)(&lds[buf][0][0][(r * 4 + (rg ^ ((r >> 1) & 3))) * 8]);
    }
#pragma unroll
    for (int nf = 0; nf < 4; ++nf) {
      const int r = 64 * wn + 16 * nf + cl;
      bfr[nf] = *(const bf16x8*)(&lds[buf][1][0][(r * 4 + (rg ^ ((r >> 1) & 3))) * 8]);
    }
    if (nl) stage_half(buf ^ 1, 0, 0, A, rowA, kt + 1);
    __builtin_amdgcn_sched_barrier(0);
    __builtin_amdgcn_s_barrier();
    asm volatile("s_waitcnt lgkmcnt(0)" ::: "memory");
    __builtin_amdgcn_sched_barrier(0);
    __builtin_amdgcn_s_setprio(1);
#pragma unroll
    for (int f = 0; f < 4; ++f)
#pragma unroll
      for (int nf = 0; nf < 4; ++nf)
        acc[f][nf] = __builtin_amdgcn_mfma_f32_16x16x32_bf16(af[f], bfr[nf], acc[f][nf], 0, 0, 0);
    __builtin_amdgcn_s_setprio(0);
    __builtin_amdgcn_s_barrier();

    // ---- phase 1: kk=0, mh=1 : read 4 A-frags (reuse B), stage B-h0(kt+1), vmcnt ----
#pragma unroll
    for (int f = 0; f < 4; ++f) {
      const int r = 128 * wm + 16 * (f + 4) + cl;
      af[f] = *(const bf16x8*)(&lds[buf][0][0][(r * 4 + (rg ^ ((r >> 1) & 3))) * 8]);
    }
    if (nl) stage_half(buf ^ 1, 1, 0, B, rowB, kt + 1);
    __builtin_amdgcn_sched_barrier(0);
    __builtin_amdgcn_s_barrier();
    asm volatile("s_waitcnt lgkmcnt(0)" ::: "memory");
    __builtin_amdgcn_sched_barrier(0);
    __builtin_amdgcn_s_setprio(1);
#pragma unroll
    for (int f = 0; f < 4; ++f)
#pragma unroll
      for (int nf = 0; nf < 4; ++nf)
        acc[f + 4][nf] = __builtin_amdgcn_mfma_f32_16x16x32_bf16(af[f], bfr[nf], acc[f + 4][nf], 0, 0, 0);
    __builtin_amdgcn_s_setprio(0);
    if (nl) asm volatile("s_waitcnt vmcnt(4)" ::: "memory");
    else    asm volatile("s_waitcnt vmcnt(0)" ::: "memory");
    __builtin_amdgcn_s_barrier();

    // ---- phase 2: kk=1, mh=0 : read 4 A-frags + 4 B-frags, stage A-h1(kt+1) ----
#pragma unroll
    for (int f = 0; f < 4; ++f) {
      const int r = 128 * wm + 16 * f + cl;
      af[f] = *(const bf16x8*)(&lds[buf][0][1][(r * 4 + (rg ^ ((r >> 1) & 3))) * 8]);
    }
#pragma unroll
    for (int nf = 0; nf < 4; ++nf) {
      const int r = 64 * wn + 16 * nf + cl;
      bfr[nf] = *(const bf16x8*)(&lds[buf][1][1][(r * 4 + (rg ^ ((r >> 1) & 3))) * 8]);
    }
    if (nl) stage_half(buf ^ 1, 0, 1, A, rowA, kt + 1);
    __builtin_amdgcn_sched_barrier(0);
    __builtin_amdgcn_s_barrier();
    asm volatile("s_waitcnt lgkmcnt(0)" ::: "memory");
    __builtin_amdgcn_sched_barrier(0);
    __builtin_amdgcn_s_setprio(1);
#pragma unroll
    for (int f = 0; f < 4; ++f)
#pragma unroll
      for (int nf = 0; nf < 4; ++nf)
        acc[f][nf] = __builtin_amdgcn_mfma_f32_16x16x32_bf16(af[f], bfr[nf], acc[f][nf], 0, 0, 0);
    __builtin_amdgcn_s_setprio(0);
    __builtin_amdgcn_s_barrier();

    // ---- phase 3: kk=1, mh=1 : read 4 A-frags (reuse B), stage B-h1(kt+1), vmcnt ----
#pragma unroll
    for (int f = 0; f < 4; ++f) {
      const int r = 128 * wm + 16 * (f + 4) + cl;
      af[f] = *(const bf16x8*)(&lds[buf][0][1][(r * 4 + (rg ^ ((r >> 1) & 3))) * 8]);
    }
    if (nl) stage_half(buf ^ 1, 1, 1, B, rowB, kt + 1);
    __builtin_amdgcn_sched_barrier(0);
    __builtin_amdgcn_s_barrier();
    asm volatile("s_waitcnt lgkmcnt(0)" ::: "memory");
    __builtin_amdgcn_sched_barrier(0);
    __builtin_amdgcn_s_setprio(1);
#pragma unroll
    for (int f = 0; f < 4; ++f)
#pragma unroll
      for (int nf = 0; nf < 4; ++nf)
        acc[f + 4][nf] = __builtin_amdgcn_mfma_f32_16x16x32_bf16(af[f], bfr[nf], acc[f + 4][nf], 0, 0, 0);
    __builtin_amdgcn_s_setprio(0);
    if (nl) asm volatile("s_waitcnt vmcnt(4)" ::: "memory");
    __builtin_amdgcn_s_barrier();

    buf ^= 1;
  }

#pragma unroll
  for (int f = 0; f < 8; ++f)
#pragma unroll
    for (int nf = 0; nf < 4; ++nf)
#pragma unroll
      for (int i = 0; i < 4; ++i) {
        const int row = bm * 256 + wm * 128 + f * 16 + rg * 4 + i;
        const int col = bn * 256 + wn * 64 + nf * 16 + cl;
        if (OUTF32)
          ((float*)Cv)[(size_t)row * N + col] = acc[f][nf][i];
        else
          ((unsigned short*)Cv)[(size_t)row * N + col] = f2bf(acc[f][nf][i]);
      }
}

// ---------------- causal GQA flash attention (round-2 version: 4 waves x 16 q, paired) ----------------
__global__ __launch_bounds__(256, 2) void attn(const unsigned short* __restrict__ QKV,
                                               const unsigned short* __restrict__ VT,
                                               unsigned short* __restrict__ O) {
  __shared__ __attribute__((aligned(16))) unsigned short Ks[2][64 * 128];
  __shared__ __attribute__((aligned(16))) unsigned short VTs[2][128 * 64];
  const int T = 2048, LD = 3072, D = 2048;
  const int jp = blockIdx.x, h = blockIdx.y, b = blockIdx.z;
  const int kvh = h >> 2;
  const int tid = threadIdx.x, lane = tid & 63, wave = tid >> 6;
  const int cl = lane & 15, rg = lane >> 4;
  const bool abit = (lane & 16) != 0, bbit = (lane & 32) != 0;
  const bool ab = abit != bbit;
  const unsigned short* Kbase = QKV + (size_t)b * T * LD + 2048 + kvh * 128;
  const unsigned short* Vbase = VT + (size_t)(b * 4 + kvh) * 128 * T;

  auto stage = [&](int sb, int k0) {
#pragma unroll
    for (int i = 0; i < 4; ++i) {
      const int Ls = i * 256 + tid;
      const int r = Ls >> 4, s = Ls & 15, c = s ^ (r & 7);
      load_lds16(Kbase + (size_t)(k0 + r) * LD + c * 8,
                 &Ks[sb][(i * 256 + (tid & 0xC0)) * 8]);
    }
#pragma unroll
    for (int i = 0; i < 4; ++i) {
      const int Ls = i * 256 + tid;
      const int r = Ls >> 3, s = Ls & 7, c = s ^ (r & 7);
      load_lds16(Vbase + (size_t)r * T + k0 + c * 8,
                 &VTs[sb][(i * 256 + (tid & 0xC0)) * 8]);
    }
  };

  const float scale = 0.08838834764831845f;  // 1/sqrt(128)

#pragma unroll 1
  for (int pass = 0; pass < 2; ++pass) {
    const int jt = pass ? (31 - jp) : jp;
    const int q0 = jt * 64;
    const int nkt = jt + 1;
    const int qrow = q0 + wave * 16 + cl;

    const unsigned short* Qp = QKV + (size_t)(b * T + qrow) * LD + h * 128;
    bf16x8 qf[4];
#pragma unroll
    for (int ks = 0; ks < 4; ++ks) qf[ks] = *(const bf16x8*)(Qp + ks * 32 + rg * 8);

    f32x4 o[8] = {};
    float m = -1e30f, l = 0.f;
    int buf = 0;

    stage(0, 0);
    __syncthreads();

#pragma unroll 1
    for (int kt = 0; kt < nkt; ++kt) {
      if (kt + 1 < nkt) stage(buf ^ 1, (kt + 1) * 64);

      f32x4 sa[4] = {};
      __builtin_amdgcn_s_setprio(1);
#pragma unroll
      for (int ks = 0; ks < 4; ++ks) {
#pragma unroll
        for (int n = 0; n < 4; ++n) {
          const int row = n * 16 + cl;
          const int p = (ks * 4 + rg) ^ (row & 7);
          const bf16x8 kf = *(const bf16x8*)(&Ks[buf][row * 128 + p * 8]);
          sa[n] = __builtin_amdgcn_mfma_f32_16x16x32_bf16(kf, qf[ks], sa[n], 0, 0, 0);
        }
      }
      __builtin_amdgcn_s_setprio(0);

      const int k0 = kt * 64;
      float p[4][4];
      float pmax = -1e30f;
      if (kt == jt) {
#pragma unroll
        for (int n = 0; n < 4; ++n)
#pragma unroll
          for (int i = 0; i < 4; ++i) {
            const int kg = k0 + n * 16 + rg * 4 + i;
            p[n][i] = (kg > qrow) ? -1e30f : sa[n][i] * scale;
            pmax = fmaxf(pmax, p[n][i]);
          }
      } else {
#pragma unroll
        for (int n = 0; n < 4; ++n)
#pragma unroll
          for (int i = 0; i < 4; ++i) {
            p[n][i] = sa[n][i] * scale;
            pmax = fmaxf(pmax, p[n][i]);
          }
      }
      pmax = fmaxf(pmax, __shfl_xor(pmax, 16));
      pmax = fmaxf(pmax, __shfl_xor(pmax, 32));

      if (!__all(pmax <= m + 8.f)) {  // T13 defer-max
        const float mnew = fmaxf(m, pmax);
        const float alpha = __expf(m - mnew);
        m = mnew;
        l *= alpha;
#pragma unroll
        for (int n2 = 0; n2 < 8; ++n2) o[n2] *= alpha;
      }

      float rs = 0.f;
#pragma unroll
      for (int n = 0; n < 4; ++n)
#pragma unroll
        for (int i = 0; i < 4; ++i) {
          p[n][i] = __expf(p[n][i] - m);
          rs += p[n][i];
        }
      rs += __shfl_xor(rs, 16);
      rs += __shfl_xor(rs, 32);
      l += rs;

      unsigned int F[2][4];
#pragma unroll
      for (int ks2 = 0; ks2 < 2; ++ks2) {
        const unsigned int pk00 = pack2(p[2 * ks2][0], p[2 * ks2][1]);
        const unsigned int pk01 = pack2(p[2 * ks2][2], p[2 * ks2][3]);
        const unsigned int pk10 = pack2(p[2 * ks2 + 1][0], p[2 * ks2 + 1][1]);
        const unsigned int pk11 = pack2(p[2 * ks2 + 1][2], p[2 * ks2 + 1][3]);
        const unsigned int s0 = bbit ? pk00 : pk10;
        const unsigned int s1 = bbit ? pk01 : pk11;
        const unsigned int r0 = (unsigned int)__shfl_xor((int)s0, 32);
        const unsigned int r1 = (unsigned int)__shfl_xor((int)s1, 32);
        const unsigned int gk0 = bbit ? pk10 : pk00;
        const unsigned int gk1 = bbit ? pk11 : pk01;
        const unsigned int t0 = ab ? gk0 : r0;
        const unsigned int t1 = ab ? gk1 : r1;
        const unsigned int u0 = (unsigned int)__shfl_xor((int)t0, 16);
        const unsigned int u1 = (unsigned int)__shfl_xor((int)t1, 16);
        const unsigned int k20 = ab ? r0 : gk0;
        const unsigned int k21 = ab ? r1 : gk1;
        F[ks2][0] = abit ? u0 : k20;
        F[ks2][1] = abit ? u1 : k21;
        F[ks2][2] = abit ? k20 : u0;
        F[ks2][3] = abit ? k21 : u1;
      }

      __builtin_amdgcn_s_setprio(1);
#pragma unroll
      for (int ks2 = 0; ks2 < 2; ++ks2) {
        uint4 fu = make_uint4(F[ks2][0], F[ks2][1], F[ks2][2], F[ks2][3]);
        const bf16x8 pf = *(const bf16x8*)&fu;
#pragma unroll
        for (int n2 = 0; n2 < 8; ++n2) {
          const int dr = n2 * 16 + cl;
          const int p2 = (ks2 * 4 + rg) ^ (dr & 7);
          const bf16x8 vf = *(const bf16x8*)(&VTs[buf][dr * 64 + p2 * 8]);
          o[n2] = __builtin_amdgcn_mfma_f32_16x16x32_bf16(vf, pf, o[n2], 0, 0, 0);
        }
      }
      __builtin_amdgcn_s_setprio(0);

      __syncthreads();
      buf ^= 1;
    }

    const float rl = __builtin_amdgcn_rcpf(l);
#pragma unroll
    for (int n2 = 0; n2 < 8; ++n2) {
      ushort4 ov;
      ov.x = f2bf(o[n2][0] * rl);
      ov.y = f2bf(o[n2][1] * rl);
      ov.z = f2bf(o[n2][2] * rl);
      ov.w = f2bf(o[n2][3] * rl);
      *(ushort4*)(O + (size_t)(b * T + qrow) * D + h * 128 + n2 * 16 + rg * 4) = ov;
    }
  }
}

extern "C" void kernel_launch(void* const* d_in, const int* in_sizes, int n_in,
                              void* d_out, int out_size, void* d_ws, size_t ws_size,
                              hipStream_t stream) {
  const float* x = (const float*)d_in[0];
  const float* Wq = (const float*)d_in[1];
  const float* Wk = (const float*)d_in[2];
  const float* Wv = (const float*)d_in[3];
  const float* Wo = (const float*)d_in[4];
  float* out = (float*)d_out;

  char* ws = (char*)d_ws;
  unsigned short* xb    = (unsigned short*)(ws);                 // x bf16, later attn O
  unsigned short* WqkvT = (unsigned short*)(ws + 16777216);      // [3072][2048]
  unsigned short* WoT   = (unsigned short*)(ws + 29360128);      // [2048][2048]
  unsigned short* QKV   = (unsigned short*)(ws + 37748736);      // [4096][3072]
  unsigned short* VTb   = (unsigned short*)(ws + 62914560);      // [8][128][2048]

  cvt_x<<<dim3(8192), dim3(256), 0, stream>>>(x, xb);
  tr_w<<<dim3(64, 64), dim3(32, 8), 0, stream>>>(Wq, WqkvT, 2048, 2048);
  tr_w<<<dim3(16, 64), dim3(32, 8), 0, stream>>>(Wk, WqkvT + (size_t)2048 * 2048, 512, 2048);
  tr_w<<<dim3(16, 64), dim3(32, 8), 0, stream>>>(Wv, WqkvT + (size_t)2560 * 2048, 512, 2048);
  tr_w<<<dim3(64, 64), dim3(32, 8), 0, stream>>>(Wo, WoT, 2048, 2048);

  gemm256<0><<<dim3(12, 16), dim3(512), 0, stream>>>(xb, WqkvT, QKV, 4096, 3072, 2048);
  tr_v<<<dim3(4, 64, 8), dim3(32, 8), 0, stream>>>(QKV, VTb);
  attn<<<dim3(16, 16, 2), dim3(256), 0, stream>>>(QKV, VTb, xb);
  gemm_bt<1><<<dim3(16, 32), dim3(256), 0, stream>>>(xb, WoT, out, 4096, 2048, 2048);
}

// Round 6
// 195.905 us; speedup vs baseline: 1.1728x; 1.0100x over previous
//
#include <hip/hip_runtime.h>
#include <hip/hip_bf16.h>

typedef __bf16 bf16x8 __attribute__((ext_vector_type(8)));
typedef float f32x4 __attribute__((ext_vector_type(4)));

__device__ __forceinline__ unsigned short f2bf(float f) {
  unsigned int u = __float_as_uint(f);
  u += 0x7fffu + ((u >> 16) & 1u);
  return (unsigned short)(u >> 16);
}

__device__ __forceinline__ unsigned int pack2(float lo, float hi) {
  __hip_bfloat162 h = __float22bfloat162_rn(float2{lo, hi});
  return *(unsigned int*)&h;
}

__device__ __forceinline__ void load_lds16(const void* g, void* l) {
  __builtin_amdgcn_global_load_lds(
      (const __attribute__((address_space(1))) unsigned int*)g,
      (__attribute__((address_space(3))) unsigned int*)l, 16, 0, 0);
}

// ---------------- elementwise f32 -> bf16 ----------------
__global__ void cvt_x(const float* __restrict__ in, unsigned short* __restrict__ out) {
  size_t i = ((size_t)blockIdx.x * 256 + threadIdx.x) * 4;
  float4 v = *(const float4*)(in + i);
  ushort4 o;
  o.x = f2bf(v.x); o.y = f2bf(v.y); o.z = f2bf(v.z); o.w = f2bf(v.w);
  *(ushort4*)(out + i) = o;
}

// ---------------- transpose f32 [R][C] -> bf16 [C][R] ----------------
__global__ void tr_w(const float* __restrict__ in, unsigned short* __restrict__ out,
                     int ldin, int ldout) {
  __shared__ float tile[32][33];
  const int c0 = blockIdx.x * 32, r0 = blockIdx.y * 32;
  const int tx = threadIdx.x, ty = threadIdx.y;
#pragma unroll
  for (int j = 0; j < 4; ++j)
    tile[ty + j * 8][tx] = in[(size_t)(r0 + ty + j * 8) * ldin + c0 + tx];
  __syncthreads();
#pragma unroll
  for (int j = 0; j < 4; ++j)
    out[(size_t)(c0 + ty + j * 8) * ldout + r0 + tx] = f2bf(tile[tx][ty + j * 8]);
}

// ---------------- V slice of QKV -> VT [b*4+kv][128][2048] ----------------
__global__ void tr_v(const unsigned short* __restrict__ QKV, unsigned short* __restrict__ VT) {
  __shared__ unsigned short tile[32][33];
  const int z = blockIdx.z, b = z >> 2, kvh = z & 3;
  const unsigned short* in = QKV + (size_t)(b * 2048) * 3072 + 2560 + kvh * 128;
  unsigned short* out = VT + (size_t)z * 128 * 2048;
  const int c0 = blockIdx.x * 32, r0 = blockIdx.y * 32;
  const int tx = threadIdx.x, ty = threadIdx.y;
#pragma unroll
  for (int j = 0; j < 4; ++j)
    tile[ty + j * 8][tx] = in[(size_t)(r0 + ty + j * 8) * 3072 + c0 + tx];
  __syncthreads();
#pragma unroll
  for (int j = 0; j < 4; ++j)
    out[(size_t)(c0 + ty + j * 8) * 2048 + r0 + tx] = tile[tx][ty + j * 8];
}

// ---------------- bf16 GEMM 256x(64*NF), 2-phase/K-tile, counted vmcnt ----------------
// 512 threads = 8 waves (2M x 4N); wave tile 128 x (16*NF). BK=64 (two k-halves of 32).
// A staged per k-half [256][32] x 2buf (64 KiB); B staged full K-tile [BN][64] x 2buf.
// Per K-tile: PH0 {read 8 A-frags(kk0) + NF B-frags(kk0); issue stage_B(next); barrier;
//   lgkmcnt(0); 8*NF MFMA; vmcnt(NF); barrier}  PH1 {same for kk1; issue 2x stage_A(next);
//   ...; vmcnt(2); barrier}. vmcnt never drains the just-issued prefetch.
template <int NF, int OUTF32>
__global__ __launch_bounds__(512, 2) void gemm256(const unsigned short* __restrict__ A,
                                                  const unsigned short* __restrict__ B,
                                                  void* __restrict__ Cv, int M, int N, int K) {
  __shared__ __attribute__((aligned(16))) unsigned short Ah[2][2][256 * 32];
  __shared__ __attribute__((aligned(16))) unsigned short Bf[2][64 * NF * 64];
  const int tid = threadIdx.x;
  const int lane = tid & 63;
  const int cl = lane & 15, rg = lane >> 4;
  const int wave = tid >> 6;
  const int wm = wave >> 2, wn = wave & 3;
  const int bm = blockIdx.y, bn = blockIdx.x;
  const int NK = K >> 6;
  const int rowA = bm * 256, rowB = bn * (64 * NF);

  f32x4 acc[8][NF] = {};

  auto stage_A = [&](int bf, int h, int kt) {
#pragma unroll
    for (int i = 0; i < 2; ++i) {
      const int L = i * 512 + tid;
      const int r = L >> 2;
      const int c = (L & 3) ^ ((r >> 1) & 3);
      load_lds16(A + (size_t)(rowA + r) * K + kt * 64 + h * 32 + c * 8,
                 &Ah[bf][h][(size_t)(i * 512 + (tid & ~63)) * 8]);
    }
  };
  auto stage_B = [&](int bf, int kt) {
#pragma unroll
    for (int i = 0; i < NF; ++i) {
      const int L = i * 512 + tid;
      const int r = L >> 3;
      const int c = (L & 7) ^ (r & 7);
      load_lds16(B + (size_t)(rowB + r) * K + kt * 64 + c * 8,
                 &Bf[bf][(size_t)(i * 512 + (tid & ~63)) * 8]);
    }
  };

  // prologue: B(NF), A-h0(2), A-h1(2); drain B+A0, keep A1 in flight
  stage_B(0, 0);
  stage_A(0, 0, 0);
  stage_A(0, 1, 0);
  asm volatile("s_waitcnt vmcnt(2)" ::: "memory");
  __builtin_amdgcn_s_barrier();

  int buf = 0;
#pragma unroll 1
  for (int kt = 0; kt < NK; ++kt) {
    const bool nl = (kt + 1 < NK);
    bf16x8 af[8], bfr[NF];

    // ---- PH0: kk = 0 ----
#pragma unroll
    for (int f = 0; f < 8; ++f) {
      const int r = 128 * wm + 16 * f + cl;
      af[f] = *(const bf16x8*)(&Ah[buf][0][(r * 4 + (rg ^ ((r >> 1) & 3))) * 8]);
    }
#pragma unroll
    for (int nf = 0; nf < NF; ++nf) {
      const int r = 16 * NF * wn + 16 * nf + cl;
      bfr[nf] = *(const bf16x8*)(&Bf[buf][(r * 8 + (rg ^ (r & 7))) * 8]);
    }
    if (nl) stage_B(buf ^ 1, kt + 1);
    __builtin_amdgcn_s_barrier();
    asm volatile("s_waitcnt lgkmcnt(0)" ::: "memory");
    __builtin_amdgcn_s_setprio(1);
#pragma unroll
    for (int f = 0; f < 8; ++f)
#pragma unroll
      for (int nf = 0; nf < NF; ++nf)
        acc[f][nf] = __builtin_amdgcn_mfma_f32_16x16x32_bf16(af[f], bfr[nf], acc[f][nf], 0, 0, 0);
    __builtin_amdgcn_s_setprio(0);
    if (nl) {
      if constexpr (NF == 3) { asm volatile("s_waitcnt vmcnt(3)" ::: "memory"); }
      else                   { asm volatile("s_waitcnt vmcnt(2)" ::: "memory"); }
    } else {
      asm volatile("s_waitcnt vmcnt(0)" ::: "memory");
    }
    __builtin_amdgcn_s_barrier();

    // ---- PH1: kk = 1 ----
#pragma unroll
    for (int f = 0; f < 8; ++f) {
      const int r = 128 * wm + 16 * f + cl;
      af[f] = *(const bf16x8*)(&Ah[buf][1][(r * 4 + (rg ^ ((r >> 1) & 3))) * 8]);
    }
#pragma unroll
    for (int nf = 0; nf < NF; ++nf) {
      const int r = 16 * NF * wn + 16 * nf + cl;
      bfr[nf] = *(const bf16x8*)(&Bf[buf][(r * 8 + ((4 + rg) ^ (r & 7))) * 8]);
    }
    if (nl) { stage_A(buf ^ 1, 0, kt + 1); stage_A(buf ^ 1, 1, kt + 1); }
    __builtin_amdgcn_s_barrier();
    asm volatile("s_waitcnt lgkmcnt(0)" ::: "memory");
    __builtin_amdgcn_s_setprio(1);
#pragma unroll
    for (int f = 0; f < 8; ++f)
#pragma unroll
      for (int nf = 0; nf < NF; ++nf)
        acc[f][nf] = __builtin_amdgcn_mfma_f32_16x16x32_bf16(af[f], bfr[nf], acc[f][nf], 0, 0, 0);
    __builtin_amdgcn_s_setprio(0);
    if (nl) asm volatile("s_waitcnt vmcnt(2)" ::: "memory");
    __builtin_amdgcn_s_barrier();

    buf ^= 1;
  }

#pragma unroll
  for (int f = 0; f < 8; ++f)
#pragma unroll
    for (int nf = 0; nf < NF; ++nf)
#pragma unroll
      for (int i = 0; i < 4; ++i) {
        const int row = bm * 256 + wm * 128 + f * 16 + rg * 4 + i;
        const int col = bn * 64 * NF + wn * 16 * NF + nf * 16 + cl;
        if (OUTF32)
          ((float*)Cv)[(size_t)row * N + col] = acc[f][nf][i];
        else
          ((unsigned short*)Cv)[(size_t)row * N + col] = f2bf(acc[f][nf][i]);
      }
}

// ---------------- causal GQA flash attention (swapped-operand, reg-P, paired) ----------------
// exp2-domain softmax (log2e folded into scale); l-sum accumulated via MFMA ones-row.
__global__ __launch_bounds__(256, 2) void attn(const unsigned short* __restrict__ QKV,
                                               const unsigned short* __restrict__ VT,
                                               unsigned short* __restrict__ O) {
  __shared__ __attribute__((aligned(16))) unsigned short Ks[2][64 * 128];
  __shared__ __attribute__((aligned(16))) unsigned short VTs[2][128 * 64];
  const int T = 2048, LD = 3072, D = 2048;
  const int jp = blockIdx.x, h = blockIdx.y, b = blockIdx.z;
  const int kvh = h >> 2;
  const int tid = threadIdx.x, lane = tid & 63, wave = tid >> 6;
  const int cl = lane & 15, rg = lane >> 4;
  const bool abit = (lane & 16) != 0, bbit = (lane & 32) != 0;
  const bool ab = abit != bbit;
  const unsigned short* Kbase = QKV + (size_t)b * T * LD + 2048 + kvh * 128;
  const unsigned short* Vbase = VT + (size_t)(b * 4 + kvh) * 128 * T;

  auto stage = [&](int sb, int k0) {
#pragma unroll
    for (int i = 0; i < 4; ++i) {
      const int Ls = i * 256 + tid;
      const int r = Ls >> 4, s = Ls & 15, c = s ^ (r & 7);
      load_lds16(Kbase + (size_t)(k0 + r) * LD + c * 8,
                 &Ks[sb][(i * 256 + (tid & 0xC0)) * 8]);
    }
#pragma unroll
    for (int i = 0; i < 4; ++i) {
      const int Ls = i * 256 + tid;
      const int r = Ls >> 3, s = Ls & 7, c = s ^ (r & 7);
      load_lds16(Vbase + (size_t)r * T + k0 + c * 8,
                 &VTs[sb][(i * 256 + (tid & 0xC0)) * 8]);
    }
  };

  const float scale2 = 0.12751742929f;  // log2(e)/sqrt(128)
  const uint4 onesu = make_uint4(0x3F803F80u, 0x3F803F80u, 0x3F803F80u, 0x3F803F80u);
  const bf16x8 ones = *(const bf16x8*)&onesu;

#pragma unroll 1
  for (int pass = 0; pass < 2; ++pass) {
    const int jt = pass ? (31 - jp) : jp;
    const int q0 = jt * 64;
    const int nkt = jt + 1;
    const int qrow = q0 + wave * 16 + cl;

    const unsigned short* Qp = QKV + (size_t)(b * T + qrow) * LD + h * 128;
    bf16x8 qf[4];
#pragma unroll
    for (int ks = 0; ks < 4; ++ks) qf[ks] = *(const bf16x8*)(Qp + ks * 32 + rg * 8);

    f32x4 o[8] = {};
    f32x4 ol = {};
    float m = -1e30f;
    int buf = 0;

    stage(0, 0);
    __syncthreads();

#pragma unroll 1
    for (int kt = 0; kt < nkt; ++kt) {
      if (kt + 1 < nkt) stage(buf ^ 1, (kt + 1) * 64);

      f32x4 sa[4] = {};
      __builtin_amdgcn_s_setprio(1);
#pragma unroll
      for (int ks = 0; ks < 4; ++ks) {
#pragma unroll
        for (int n = 0; n < 4; ++n) {
          const int row = n * 16 + cl;
          const int p = (ks * 4 + rg) ^ (row & 7);
          const bf16x8 kf = *(const bf16x8*)(&Ks[buf][row * 128 + p * 8]);
          sa[n] = __builtin_amdgcn_mfma_f32_16x16x32_bf16(kf, qf[ks], sa[n], 0, 0, 0);
        }
      }
      __builtin_amdgcn_s_setprio(0);

      const int k0 = kt * 64;
      float p[4][4];
      float pmax = -1e30f;
      if (kt == jt) {
#pragma unroll
        for (int n = 0; n < 4; ++n)
#pragma unroll
          for (int i = 0; i < 4; ++i) {
            const int kg = k0 + n * 16 + rg * 4 + i;
            p[n][i] = (kg > qrow) ? -1e30f : sa[n][i] * scale2;
            pmax = fmaxf(pmax, p[n][i]);
          }
      } else {
#pragma unroll
        for (int n = 0; n < 4; ++n)
#pragma unroll
          for (int i = 0; i < 4; ++i) {
            p[n][i] = sa[n][i] * scale2;
            pmax = fmaxf(pmax, p[n][i]);
          }
      }
      pmax = fmaxf(pmax, __shfl_xor(pmax, 16));
      pmax = fmaxf(pmax, __shfl_xor(pmax, 32));

      if (!__all(pmax <= m + 11.0f)) {  // T13 defer-max (log2 units)
        const float mnew = fmaxf(m, pmax);
        const float alpha = exp2f(m - mnew);
        m = mnew;
        ol *= alpha;
#pragma unroll
        for (int n2 = 0; n2 < 8; ++n2) o[n2] *= alpha;
      }

#pragma unroll
      for (int n = 0; n < 4; ++n)
#pragma unroll
        for (int i = 0; i < 4; ++i)
          p[n][i] = exp2f(p[n][i] - m);

      unsigned int F[2][4];
#pragma unroll
      for (int ks2 = 0; ks2 < 2; ++ks2) {
        const unsigned int pk00 = pack2(p[2 * ks2][0], p[2 * ks2][1]);
        const unsigned int pk01 = pack2(p[2 * ks2][2], p[2 * ks2][3]);
        const unsigned int pk10 = pack2(p[2 * ks2 + 1][0], p[2 * ks2 + 1][1]);
        const unsigned int pk11 = pack2(p[2 * ks2 + 1][2], p[2 * ks2 + 1][3]);
        const unsigned int s0 = bbit ? pk00 : pk10;
        const unsigned int s1 = bbit ? pk01 : pk11;
        const unsigned int r0 = (unsigned int)__shfl_xor((int)s0, 32);
        const unsigned int r1 = (unsigned int)__shfl_xor((int)s1, 32);
        const unsigned int gk0 = bbit ? pk10 : pk00;
        const unsigned int gk1 = bbit ? pk11 : pk01;
        const unsigned int t0 = ab ? gk0 : r0;
        const unsigned int t1 = ab ? gk1 : r1;
        const unsigned int u0 = (unsigned int)__shfl_xor((int)t0, 16);
        const unsigned int u1 = (unsigned int)__shfl_xor((int)t1, 16);
        const unsigned int k20 = ab ? r0 : gk0;
        const unsigned int k21 = ab ? r1 : gk1;
        F[ks2][0] = abit ? u0 : k20;
        F[ks2][1] = abit ? u1 : k21;
        F[ks2][2] = abit ? k20 : u0;
        F[ks2][3] = abit ? k21 : u1;
      }

      __builtin_amdgcn_s_setprio(1);
#pragma unroll
      for (int ks2 = 0; ks2 < 2; ++ks2) {
        uint4 fu = make_uint4(F[ks2][0], F[ks2][1], F[ks2][2], F[ks2][3]);
        const bf16x8 pf = *(const bf16x8*)&fu;
        ol = __builtin_amdgcn_mfma_f32_16x16x32_bf16(ones, pf, ol, 0, 0, 0);
#pragma unroll
        for (int n2 = 0; n2 < 8; ++n2) {
          const int dr = n2 * 16 + cl;
          const int p2 = (ks2 * 4 + rg) ^ (dr & 7);
          const bf16x8 vf = *(const bf16x8*)(&VTs[buf][dr * 64 + p2 * 8]);
          o[n2] = __builtin_amdgcn_mfma_f32_16x16x32_bf16(vf, pf, o[n2], 0, 0, 0);
        }
      }
      __builtin_amdgcn_s_setprio(0);

      __syncthreads();
      buf ^= 1;
    }

    const float rl = __builtin_amdgcn_rcpf(ol[0]);
#pragma unroll
    for (int n2 = 0; n2 < 8; ++n2) {
      ushort4 ov;
      ov.x = f2bf(o[n2][0] * rl);
      ov.y = f2bf(o[n2][1] * rl);
      ov.z = f2bf(o[n2][2] * rl);
      ov.w = f2bf(o[n2][3] * rl);
      *(ushort4*)(O + (size_t)(b * T + qrow) * D + h * 128 + n2 * 16 + rg * 4) = ov;
    }
  }
}

extern "C" void kernel_launch(void* const* d_in, const int* in_sizes, int n_in,
                              void* d_out, int out_size, void* d_ws, size_t ws_size,
                              hipStream_t stream) {
  const float* x = (const float*)d_in[0];
  const float* Wq = (const float*)d_in[1];
  const float* Wk = (const float*)d_in[2];
  const float* Wv = (const float*)d_in[3];
  const float* Wo = (const float*)d_in[4];
  float* out = (float*)d_out;

  char* ws = (char*)d_ws;
  unsigned short* xb    = (unsigned short*)(ws);                 // x bf16, later attn O
  unsigned short* WqkvT = (unsigned short*)(ws + 16777216);      // [3072][2048]
  unsigned short* WoT   = (unsigned short*)(ws + 29360128);      // [2048][2048]
  unsigned short* QKV   = (unsigned short*)(ws + 37748736);      // [4096][3072]
  unsigned short* VTb   = (unsigned short*)(ws + 62914560);      // [8][128][2048]

  cvt_x<<<dim3(8192), dim3(256), 0, stream>>>(x, xb);
  tr_w<<<dim3(64, 64), dim3(32, 8), 0, stream>>>(Wq, WqkvT, 2048, 2048);
  tr_w<<<dim3(16, 64), dim3(32, 8), 0, stream>>>(Wk, WqkvT + (size_t)2048 * 2048, 512, 2048);
  tr_w<<<dim3(16, 64), dim3(32, 8), 0, stream>>>(Wv, WqkvT + (size_t)2560 * 2048, 512, 2048);
  tr_w<<<dim3(64, 64), dim3(32, 8), 0, stream>>>(Wo, WoT, 2048, 2048);

  gemm256<3, 0><<<dim3(16, 16), dim3(512), 0, stream>>>(xb, WqkvT, QKV, 4096, 3072, 2048);
  tr_v<<<dim3(4, 64, 8), dim3(32, 8), 0, stream>>>(QKV, VTb);
  attn<<<dim3(16, 16, 2), dim3(256), 0, stream>>>(QKV, VTb, xb);
  gemm256<2, 1><<<dim3(16, 16), dim3(512), 0, stream>>>(xb, WoT, out, 4096, 2048, 2048);
}